// Round 17
// baseline (107.001 us; speedup 1.0000x reference)
//
#include <hip/hip_runtime.h>
#include <math.h>

#define N_NODES 16384
#define DIM 256
#define KNBR 16
#define NEDGE 128
#define KZ 384            // REP layout: node (256) | edge-histogram (128)

typedef __bf16 bf16x8 __attribute__((ext_vector_type(8)));
typedef float f32x4 __attribute__((ext_vector_type(4)));
typedef short short4v __attribute__((ext_vector_type(4)));
typedef short short8v __attribute__((ext_vector_type(8)));
typedef unsigned int u32;
typedef u32 u32x4 __attribute__((ext_vector_type(4)));
typedef unsigned short u16;

__device__ __forceinline__ u16 f2bf(float x) {
    u32 u = __builtin_bit_cast(u32, x);
    u = u + 0x7FFFu + ((u >> 16) & 1u);   // round-to-nearest-even
    return (u16)(u >> 16);
}
__device__ __forceinline__ float bf2f(u16 h) {
    u32 u = ((u32)h) << 16;
    return __builtin_bit_cast(float, u);
}
__device__ __forceinline__ float readlane_f(float v, int l) {
    return __builtin_bit_cast(float, __builtin_amdgcn_readlane(__builtin_bit_cast(int, v), l));
}

// XOR-swizzled LDS index (16B-unit swizzle) for a [rows][64] bf16 tile.
__device__ __forceinline__ int lds_swz(int row, int k) {
    return (row << 6) + ((((k >> 3) ^ (row & 7)) << 3) | (k & 7));
}

// ---------------------------------------------------------------------------
// prep (2560 blocks): merged pack + tiny-GEMM builds. Single-bf16 M.
//  b<256       : Mcat row b = (W_node @ attenW) row b, bf16
//  b in [256,384): e=b-256: EM[e] = (Eemb[e] @ W_nodeL) @ attenW -> Mcat 256+e
//  b in [384,512): e=b-384: G[e][d] = Eemb[e] @ W_nb[256:512,d] -> WnbTh2 col 256+e
//  b>=512      : pack Xh = bf16(X) (vectorized float4->short4);
//                WnbTh2 node cols; W1h transpose
// b_node is softmax-invariant (constant over k) -> dropped.
// ---------------------------------------------------------------------------
__global__ __launch_bounds__(256) void prep(const float* __restrict__ X,
                                            const float* __restrict__ W_nb,
                                            const float* __restrict__ W1,
                                            const float* __restrict__ W_node,
                                            const float* __restrict__ attenW,
                                            const float* __restrict__ Eemb,
                                            u16* __restrict__ Xh,
                                            u16* __restrict__ WnbTh2,
                                            u16* __restrict__ W1h,
                                            u16* __restrict__ Mhi) {
    __shared__ float F[DIM];
    const int b = blockIdx.x;
    const int d = threadIdx.x;
    if (b < 256) {
        float acc = 0.f;
        for (int e = 0; e < DIM; ++e)
            acc = fmaf(W_node[b * DIM + e], attenW[e * DIM + d], acc);
        Mhi[b * DIM + d] = f2bf(acc);
    } else if (b < 384) {
        const int e = b - 256;
        float f = 0.f;
        for (int dd = 0; dd < DIM; ++dd)
            f = fmaf(Eemb[e * DIM + dd], W_node[(DIM + dd) * DIM + d], f);
        F[d] = f;
        __syncthreads();
        float acc = 0.f;
        for (int jj = 0; jj < DIM; ++jj)
            acc = fmaf(F[jj], attenW[jj * DIM + d], acc);
        Mhi[(DIM + e) * DIM + d] = f2bf(acc);
    } else if (b < 512) {
        const int e = b - 384;
        float acc = 0.f;
        for (int dd = 0; dd < DIM; ++dd)
            acc = fmaf(Eemb[e * DIM + dd], W_nb[(DIM + dd) * DIM + d], acc);
        WnbTh2[d * KZ + DIM + e] = f2bf(acc);
    } else {
        // X pack: float4 -> short4, 1048576 vec4 units, exactly 2 iters/thread
        const int XN4 = (N_NODES * DIM) / 4;
        for (int i = (b - 512) * 256 + d; i < XN4; i += 2048 * 256) {
            float4 v = ((const float4*)X)[i];
            short4v s = {(short)f2bf(v.x), (short)f2bf(v.y),
                         (short)f2bf(v.z), (short)f2bf(v.w)};
            ((short4v*)Xh)[i] = s;
        }
        // small transposed packs
        const int WE = DIM * DIM;            // 65536
        const int WE1 = 64 * DIM;            // 16384
        for (int i = (b - 512) * 256 + d; i < WE + WE1; i += 2048 * 256) {
            if (i < WE) {
                int c = i >> 8, k = i & 255;
                WnbTh2[c * KZ + k] = f2bf(W_nb[k * DIM + c]);
            } else {
                int j = i - WE;              // j = n*256 + k, n<64
                int n = j >> 8, k = j & 255;
                W1h[j] = f2bf(W1[k * 64 + n]);
            }
        }
    }
}

// ---------------------------------------------------------------------------
// gemm_z: [z1|EZ][16384,384] = Xh @ Mcat^T (single bf16 product).
// 1D grid (384), COL-ADJACENT order: c=bid%3, m=bid/3 -> the 3 col-blocks
// sharing an A-panel run back-to-back, so A re-reads hit L2 (R16: x-major
// 2D order spaced them ~128 dispatches apart -> panel evicted).
// Epilogue: col<256 -> Zh bf16; col>=256 -> EZh bf16.
// ---------------------------------------------------------------------------
__global__ __launch_bounds__(256, 2) void gemm_z(const u16* __restrict__ Xh,
                                                 const u16* __restrict__ Mhi,
                                                 u16* __restrict__ Zh,
                                                 u16* __restrict__ EZh) {
    constexpr int BM = 128, BN = 128, BK = 64;
    constexpr int Kd = DIM;
    __shared__ short Ah[BM * BK], Bh[BN * BK];
    const int tid = threadIdx.x;
    const int bid = blockIdx.x;
    const int m0 = (bid / 3) * BM, n0 = (bid % 3) * BN;
    const int w = tid >> 6, lane = tid & 63;
    const int wr = (w >> 1) * 64, wc = (w & 1) * 64;
    const int lrow = lane & 15, lkg = lane >> 4;

    f32x4 acc[4][4] = {};

    for (int k0 = 0; k0 < Kd; k0 += BK) {
#pragma unroll
        for (int i = 0; i < 4; ++i) {
            int idx = i * 256 + tid;
            int r = idx >> 3, c8 = (idx & 7) << 3;
            int li = lds_swz(r, c8);
            *(short8v*)&Ah[li] = *(const short8v*)&Xh[(size_t)(m0 + r) * Kd + k0 + c8];
            *(short8v*)&Bh[li] = *(const short8v*)&Mhi[(size_t)(n0 + r) * Kd + k0 + c8];
        }
        __syncthreads();
#pragma unroll
        for (int kk = 0; kk < 2; ++kk) {
            const int kof = kk * 32 + lkg * 8;
            bf16x8 a[4], b[4];
#pragma unroll
            for (int i = 0; i < 4; ++i) a[i] = *(const bf16x8*)&Ah[lds_swz(wr + i * 16 + lrow, kof)];
#pragma unroll
            for (int j = 0; j < 4; ++j) b[j] = *(const bf16x8*)&Bh[lds_swz(wc + j * 16 + lrow, kof)];
#pragma unroll
            for (int i = 0; i < 4; ++i)
#pragma unroll
                for (int j = 0; j < 4; ++j)
                    acc[i][j] = __builtin_amdgcn_mfma_f32_16x16x32_bf16(a[i], b[j], acc[i][j], 0, 0, 0);
        }
        __syncthreads();
    }
#pragma unroll
    for (int i = 0; i < 4; ++i)
#pragma unroll
        for (int j = 0; j < 4; ++j)
#pragma unroll
            for (int r = 0; r < 4; ++r) {
                int row = m0 + wr + i * 16 + lkg * 4 + r;
                int col = n0 + wc + j * 16 + lrow;
                if (col < DIM)
                    Zh[(size_t)row * DIM + col] = f2bf(acc[i][j][r]);
                else
                    EZh[(size_t)row * NEDGE + (col - DIM)] = f2bf(acc[i][j][r]);
            }
}

// ---------------------------------------------------------------------------
// gather_fused v7: loop1 = flash-style logit + out-aggregation; loop2 =
// in-aggregation + in-edge histogram (dependency-free from loop1); out-edge
// histogram = load-free readlane sweep after softmax. No fences, no local
// arrays, no LDS. 8 waves/block.
// ---------------------------------------------------------------------------
#define NPB 8
__global__ __launch_bounds__(64 * NPB) void gather_fused(
    const u16* __restrict__ Xh, const u16* __restrict__ Zh,
    const u16* __restrict__ EZh,
    const int* __restrict__ in_idx, const int* __restrict__ in_edge,
    const float* __restrict__ in_mask, const int* __restrict__ out_idx,
    const int* __restrict__ out_edge, const float* __restrict__ out_mask,
    u16* __restrict__ REPh) {
    const int tid = threadIdx.x;
    const int w = tid >> 6, lane = tid & 63;
    const int n = blockIdx.x * NPB + w;
    const int nu = __builtin_amdgcn_readfirstlane(n);
    const int l31 = lane & 31, h = lane >> 5;
    const int l15 = lane & 15;

    // per-lane tables: lane l15 holds neighbor-l15 entry (readlane sources)
    const int oi_l = out_idx[nu * KNBR + l15];
    const int ii_l = in_idx[nu * KNBR + l15];
    const float om_l = out_mask[nu * KNBR + l15];
    const float im_l = in_mask[nu * KNBR + l15];
    const int oe_l = out_edge[nu * KNBR + l15];
    const int ie_l = in_edge[nu * KNBR + l15];
    const float ez_l = bf2f(EZh[(size_t)n * NEDGE + oe_l]);   // EZ for k=l15
    const int k_lane = ((lane & 7) << 1) | h;
    const float om_v = out_mask[nu * KNBR + k_lane];

    // z1 slice: lane covers dims [8*l31, 8*l31+8)
    float zr[8];
    {
        short8v zvv = *(const short8v*)&Zh[(size_t)n * DIM + l31 * 8];
#pragma unroll
        for (int c = 0; c < 8; ++c) zr[c] = bf2f((u16)zvv[c]);
    }

    const char* Xb = (const char*)Xh;
    const u32 lofs = (u32)l31 * 16u;

    // loop1: fused logit + out-aggregation; iter j covers k=2j (lanes 0-31)
    // and k=2j+1 (lanes 32-63); row consumed for BOTH in one pass.
    float acc_o[8] = {};
    float s_run = 0.f, esel = 0.f;
#pragma unroll
    for (int j = 0; j < 8; ++j) {
        const int ro0 = __builtin_amdgcn_readlane(oi_l, 2 * j);
        const int ro1 = __builtin_amdgcn_readlane(oi_l, 2 * j + 1);
        const int ro = h ? ro1 : ro0;
        u32x4 xv = *(const u32x4*)(Xb + (((u32)ro << 9) + lofs));
        short8v sv = __builtin_bit_cast(short8v, xv);
        float q = 0.f;
#pragma unroll
        for (int c = 0; c < 8; ++c) q = fmaf(bf2f((u16)sv[c]), zr[c], q);
        q += __shfl_xor(q, 1);
        q += __shfl_xor(q, 2);
        q += __shfl_xor(q, 4);
        q += __shfl_xor(q, 8);
        q += __shfl_xor(q, 16);
        const float ez0 = readlane_f(ez_l, 2 * j);
        const float ez1 = readlane_f(ez_l, 2 * j + 1);
        q += h ? ez1 : ez0;
        const float eo = __expf(q);              // unnormalized weight, own k
        const float ec = __shfl_xor(eo, 32);     // other half's e
        s_run += eo + ec;                        // adds e(2j)+e(2j+1) once
        if ((lane & 7) == j) esel = eo;          // keep e for k_lane
        const float om0 = readlane_f(om_l, 2 * j);
        const float om1 = readlane_f(om_l, 2 * j + 1);
        const float wgt = eo * (h ? om1 : om0);
#pragma unroll
        for (int c = 0; c < 8; ++c) acc_o[c] = fmaf(wgt, bf2f((u16)sv[c]), acc_o[c]);
    }

    // loop2: in-aggregation + in-edge histogram — independent of loop1.
    float acc_i[8] = {};
    const int my0 = 2 * lane, my1 = 2 * lane + 1;
    float hb0 = 0.f, hb1 = 0.f;
#pragma unroll
    for (int j = 0; j < 8; ++j) {
        const int ri0 = __builtin_amdgcn_readlane(ii_l, 2 * j);
        const int ri1 = __builtin_amdgcn_readlane(ii_l, 2 * j + 1);
        const int ri = h ? ri1 : ri0;
        u32x4 xv = *(const u32x4*)(Xb + (((u32)ri << 9) + lofs));
        short8v sv = __builtin_bit_cast(short8v, xv);
        const float im0 = readlane_f(im_l, 2 * j);
        const float im1 = readlane_f(im_l, 2 * j + 1);
        const float imk = h ? im1 : im0;
#pragma unroll
        for (int c = 0; c < 8; ++c) acc_i[c] = fmaf(imk, bf2f((u16)sv[c]), acc_i[c]);
        const int ie0 = __builtin_amdgcn_readlane(ie_l, 2 * j);
        const int ie1 = __builtin_amdgcn_readlane(ie_l, 2 * j + 1);
        hb0 += (ie0 == my0 ? im0 : 0.f) + (ie1 == my0 ? im1 : 0.f);
        hb1 += (ie0 == my1 ? im0 : 0.f) + (ie1 == my1 ? im1 : 0.f);
    }

    // softmax scalars (only now needed)
    const float inv_s = 1.0f / s_run;
    const float wt = esel * om_v * inv_s;        // alpha*om for k_lane

    // out-edge histogram: load-free readlane+cmp sweep
#pragma unroll
    for (int k = 0; k < KNBR; ++k) {
        const int lk = (k & 1) * 32 + (k >> 1);  // lane holding k's wt
        const float wtk = readlane_f(wt, lk);
        const int oek = __builtin_amdgcn_readlane(oe_l, k);
        hb0 += (oek == my0 ? wtk : 0.f);
        hb1 += (oek == my1 ? wtk : 0.f);
    }

    // fold halves; REPnode = out/s + in, from lanes 0-31
#pragma unroll
    for (int c = 0; c < 8; ++c) {
        float to = acc_o[c] + __shfl_xor(acc_o[c], 32);
        float ti = acc_i[c] + __shfl_xor(acc_i[c], 32);
        acc_o[c] = to * inv_s + ti;
    }
    if (lane < 32) {
        short8v ov;
#pragma unroll
        for (int c = 0; c < 8; ++c) ov[c] = (short)f2bf(acc_o[c]);
        *(short8v*)&REPh[(size_t)n * KZ + l31 * 8] = ov;
    }
    u32 pk = (u32)f2bf(hb0) | ((u32)f2bf(hb1) << 16);
    *(u32*)&REPh[(size_t)n * KZ + DIM + lane * 2] = pk;
}

// ---------------------------------------------------------------------------
// gemm_h: out[16384,256] f32 = [REPnode|cnt] @ WnbTh2^T + Xh + 2*b_nb;
// residual from bf16 Xh. Also writes Hh bf16 (MFMA MLP). K=384.
// 1D grid (256), COL-ADJACENT order: c=bid&1, m=bid>>1 -> both col-blocks
// of an A-panel run adjacently for L2 reuse of the 12.6MB REPh.
// ---------------------------------------------------------------------------
__global__ __launch_bounds__(256, 3) void gemm_h(const u16* __restrict__ A,
                                                 const u16* __restrict__ B,
                                                 const u16* __restrict__ Xres,
                                                 const float* __restrict__ b_nb,
                                                 float* __restrict__ out,
                                                 u16* __restrict__ Hh) {
    constexpr int BM = 128, BN = 128, BK = 64;
    constexpr int Kd = KZ, Nd = DIM;
    __shared__ short Ah[BM * BK], Bh[BN * BK];
    const int tid = threadIdx.x;
    const int bid = blockIdx.x;
    const int m0 = (bid >> 1) * BM, n0 = (bid & 1) * BN;
    const int w = tid >> 6, lane = tid & 63;
    const int wr = (w >> 1) * 64, wc = (w & 1) * 64;
    const int lrow = lane & 15, lkg = lane >> 4;

    f32x4 acc[4][4] = {};

    for (int k0 = 0; k0 < Kd; k0 += BK) {
#pragma unroll
        for (int i = 0; i < 4; ++i) {
            int idx = i * 256 + tid;
            int r = idx >> 3, c8 = (idx & 7) << 3;
            int li = lds_swz(r, c8);
            *(short8v*)&Ah[li] = *(const short8v*)&A[(size_t)(m0 + r) * Kd + k0 + c8];
            *(short8v*)&Bh[li] = *(const short8v*)&B[(size_t)(n0 + r) * Kd + k0 + c8];
        }
        __syncthreads();
#pragma unroll
        for (int kk = 0; kk < 2; ++kk) {
            const int kof = kk * 32 + lkg * 8;
            bf16x8 a[4], b[4];
#pragma unroll
            for (int i = 0; i < 4; ++i) a[i] = *(const bf16x8*)&Ah[lds_swz(wr + i * 16 + lrow, kof)];
#pragma unroll
            for (int j = 0; j < 4; ++j) b[j] = *(const bf16x8*)&Bh[lds_swz(wc + j * 16 + lrow, kof)];
#pragma unroll
            for (int i = 0; i < 4; ++i)
#pragma unroll
                for (int j = 0; j < 4; ++j)
                    acc[i][j] = __builtin_amdgcn_mfma_f32_16x16x32_bf16(a[i], b[j], acc[i][j], 0, 0, 0);
        }
        __syncthreads();
    }
#pragma unroll
    for (int i = 0; i < 4; ++i)
#pragma unroll
        for (int j = 0; j < 4; ++j)
#pragma unroll
            for (int r = 0; r < 4; ++r) {
                int row = m0 + wr + i * 16 + lkg * 4 + r;
                int col = n0 + wc + j * 16 + lrow;
                size_t off = (size_t)row * Nd + col;
                float hv = acc[i][j][r] + bf2f(Xres[off]) + 2.0f * b_nb[col];
                out[off] = hv;
                Hh[off] = f2bf(hv);
            }
}

// ---------------------------------------------------------------------------
// mlp_mfma + finalize: unchanged (deterministic 2-stage readout).
// ---------------------------------------------------------------------------
__global__ __launch_bounds__(256) void mlp_mfma(const u16* __restrict__ Hh,
                                                const u16* __restrict__ W1h,
                                                const float* __restrict__ b1,
                                                const float* __restrict__ W2,
                                                float* __restrict__ partials) {
    constexpr int BM = 128, BN = 64, BK = 64;
    constexpr int Kd = DIM;
    __shared__ short Ah[BM * BK], Bh[BN * BK];
    __shared__ float red[4][BN];
    const int tid = threadIdx.x;
    const int m0 = blockIdx.x * BM;
    const int w = tid >> 6, lane = tid & 63;
    const int wr = w * 32;
    const int lrow = lane & 15, lkg = lane >> 4;

    f32x4 acc[2][4] = {};

    for (int k0 = 0; k0 < Kd; k0 += BK) {
#pragma unroll
        for (int i = 0; i < 4; ++i) {
            int idx = i * 256 + tid;
            int r = idx >> 3, c8 = (idx & 7) << 3;
            *(short8v*)&Ah[lds_swz(r, c8)] =
                *(const short8v*)&Hh[(size_t)(m0 + r) * Kd + k0 + c8];
        }
#pragma unroll
        for (int i = 0; i < 2; ++i) {
            int idx = i * 256 + tid;
            if (idx < 512) {
                int r = idx >> 3, c8 = (idx & 7) << 3;
                *(short8v*)&Bh[lds_swz(r, c8)] =
                    *(const short8v*)&W1h[(size_t)r * Kd + k0 + c8];
            }
        }
        __syncthreads();
#pragma unroll
        for (int kk = 0; kk < 2; ++kk) {
            const int kof = kk * 32 + lkg * 8;
            bf16x8 a[2], b[4];
#pragma unroll
            for (int i = 0; i < 2; ++i) a[i] = *(const bf16x8*)&Ah[lds_swz(wr + i * 16 + lrow, kof)];
#pragma unroll
            for (int j = 0; j < 4; ++j) b[j] = *(const bf16x8*)&Bh[lds_swz(j * 16 + lrow, kof)];
#pragma unroll
            for (int i = 0; i < 2; ++i)
#pragma unroll
                for (int j = 0; j < 4; ++j)
                    acc[i][j] = __builtin_amdgcn_mfma_f32_16x16x32_bf16(a[i], b[j], acc[i][j], 0, 0, 0);
        }
        __syncthreads();
    }
    float cs[4];
#pragma unroll
    for (int j = 0; j < 4; ++j) {
        const float bj = b1[j * 16 + lrow];
        float sv = 0.f;
#pragma unroll
        for (int i = 0; i < 2; ++i)
#pragma unroll
            for (int r = 0; r < 4; ++r) sv += fmaxf(acc[i][j][r] + bj, 0.f);
        cs[j] = sv;
    }
#pragma unroll
    for (int j = 0; j < 4; ++j) {
        cs[j] += __shfl_xor(cs[j], 16);
        cs[j] += __shfl_xor(cs[j], 32);
    }
    if (lkg == 0) {
#pragma unroll
        for (int j = 0; j < 4; ++j) red[w][j * 16 + lrow] = cs[j];
    }
    __syncthreads();
    if (tid < 64) {
        float t = red[0][tid] + red[1][tid] + red[2][tid] + red[3][tid];
        float h0 = t * W2[tid * 2 + 0];
        float h1 = t * W2[tid * 2 + 1];
#pragma unroll
        for (int off = 32; off > 0; off >>= 1) {
            h0 += __shfl_down(h0, off);
            h1 += __shfl_down(h1, off);
        }
        if (tid == 0) {
            partials[blockIdx.x * 2 + 0] = h0;
            partials[blockIdx.x * 2 + 1] = h1;
        }
    }
}

__global__ void finalize(const float* __restrict__ partials,
                         const float* __restrict__ b2, float* __restrict__ out) {
    const int l = threadIdx.x;
    float h0 = 0.f, h1 = 0.f;
    for (int i = l; i < 128; i += 64) {
        h0 += partials[2 * i + 0];
        h1 += partials[2 * i + 1];
    }
#pragma unroll
    for (int off = 32; off > 0; off >>= 1) {
        h0 += __shfl_down(h0, off);
        h1 += __shfl_down(h1, off);
    }
    if (l == 0) {
        h0 += (float)N_NODES * b2[0];
        h1 += (float)N_NODES * b2[1];
        const float m = fmaxf(h0, h1);
        const float e0 = __expf(h0 - m), e1 = __expf(h1 - m);
        out[(size_t)N_NODES * DIM + 0] = e0 / (e0 + e1);
        out[(size_t)N_NODES * DIM + 1] = e1 / (e0 + e1);
    }
}

extern "C" void kernel_launch(void* const* d_in, const int* in_sizes, int n_in,
                              void* d_out, int out_size, void* d_ws, size_t ws_size,
                              hipStream_t stream) {
    const float* X = (const float*)d_in[0];
    const int* in_idx = (const int*)d_in[1];
    const int* in_edge = (const int*)d_in[2];
    const float* in_mask = (const float*)d_in[3];
    const int* out_idx = (const int*)d_in[4];
    const int* out_edge = (const int*)d_in[5];
    const float* out_mask = (const float*)d_in[6];
    const float* Eemb = (const float*)d_in[7];
    const float* W_nb = (const float*)d_in[8];
    const float* b_nb = (const float*)d_in[9];
    const float* W_node = (const float*)d_in[10];
    // d_in[11] = b_node: softmax-invariant -> unused
    const float* attenW = (const float*)d_in[12];
    const float* W1 = (const float*)d_in[13];
    const float* b1 = (const float*)d_in[14];
    const float* W2 = (const float*)d_in[15];
    const float* b2 = (const float*)d_in[16];
    float* out = (float*)d_out;

    char* ws = (char*)d_ws;
    // Overlays (stream-ordered): Zh+EZh dead after gather_fused -> Hh reuses.
    u16* Zh = (u16*)ws;                          // 8 MiB   [0, 8M)
    u16* EZh = (u16*)(ws + 8388608);             // 4 MiB   [8M, 12M)
    u16* Hh = (u16*)ws;                          // 8 MiB   [0, 8M) reuse
    u16* REPh = (u16*)(ws + 16777216);           // 12.58 MiB
    u16* Xh = (u16*)(ws + 29360128);             // 8 MiB
    u16* WnbTh2 = (u16*)(ws + 37748736);         // 192 KiB (256x384)
    u16* Mhi = (u16*)(ws + 37945344);            // 192 KiB (384x256)
    u16* W1h = (u16*)(ws + 38338560);            // 32 KiB
    float* partials = (float*)(ws + 38371328);   // 1 KiB

    prep<<<2560, 256, 0, stream>>>(X, W_nb, W1, W_node, attenW, Eemb,
                                   Xh, WnbTh2, W1h, Mhi);
    gemm_z<<<384, 256, 0, stream>>>(Xh, Mhi, Zh, EZh);
    gather_fused<<<N_NODES / NPB, 64 * NPB, 0, stream>>>(
        Xh, Zh, EZh, in_idx, in_edge, in_mask, out_idx, out_edge, out_mask, REPh);
    gemm_h<<<256, 256, 0, stream>>>(REPh, WnbTh2, Xh, b_nb, out, Hh);
    mlp_mfma<<<N_NODES / 128, 256, 0, stream>>>(Hh, W1h, b1, W2, partials);
    finalize<<<1, 64, 0, stream>>>(partials, b2, out);
}

// Round 18
// 98.150 us; speedup vs baseline: 1.0902x; 1.0902x over previous
//
#include <hip/hip_runtime.h>
#include <math.h>

#define N_NODES 16384
#define DIM 256
#define KNBR 16
#define NEDGE 128
#define KZ 384            // REP layout: node (256) | edge-histogram (128)

typedef __bf16 bf16x8 __attribute__((ext_vector_type(8)));
typedef float f32x4 __attribute__((ext_vector_type(4)));
typedef short short4v __attribute__((ext_vector_type(4)));
typedef short short8v __attribute__((ext_vector_type(8)));
typedef unsigned int u32;
typedef u32 u32x4 __attribute__((ext_vector_type(4)));
typedef unsigned short u16;

__device__ __forceinline__ u16 f2bf(float x) {
    u32 u = __builtin_bit_cast(u32, x);
    u = u + 0x7FFFu + ((u >> 16) & 1u);   // round-to-nearest-even
    return (u16)(u >> 16);
}
__device__ __forceinline__ float bf2f(u16 h) {
    u32 u = ((u32)h) << 16;
    return __builtin_bit_cast(float, u);
}
__device__ __forceinline__ float readlane_f(float v, int l) {
    return __builtin_bit_cast(float, __builtin_amdgcn_readlane(__builtin_bit_cast(int, v), l));
}

// XOR-swizzled LDS index (16B-unit swizzle) for a [rows][64] bf16 tile.
__device__ __forceinline__ int lds_swz(int row, int k) {
    return (row << 6) + ((((k >> 3) ^ (row & 7)) << 3) | (k & 7));
}

// ---------------------------------------------------------------------------
// prep (2560 blocks): merged pack + tiny-GEMM builds. Single-bf16 M.
//  b<256       : Mcat row b = (W_node @ attenW) row b, bf16
//  b in [256,384): e=b-256: EM[e] = (Eemb[e] @ W_nodeL) @ attenW -> Mcat 256+e
//  b in [384,512): e=b-384: G[e][d] = Eemb[e] @ W_nb[256:512,d] -> WnbTh2 col 256+e
//  b>=512      : pack Xh = bf16(X) (vectorized float4->short4);
//                WnbTh2 node cols; W1h transpose
// b_node is softmax-invariant (constant over k) -> dropped.
// ---------------------------------------------------------------------------
__global__ __launch_bounds__(256) void prep(const float* __restrict__ X,
                                            const float* __restrict__ W_nb,
                                            const float* __restrict__ W1,
                                            const float* __restrict__ W_node,
                                            const float* __restrict__ attenW,
                                            const float* __restrict__ Eemb,
                                            u16* __restrict__ Xh,
                                            u16* __restrict__ WnbTh2,
                                            u16* __restrict__ W1h,
                                            u16* __restrict__ Mhi) {
    __shared__ float F[DIM];
    const int b = blockIdx.x;
    const int d = threadIdx.x;
    if (b < 256) {
        float acc = 0.f;
        for (int e = 0; e < DIM; ++e)
            acc = fmaf(W_node[b * DIM + e], attenW[e * DIM + d], acc);
        Mhi[b * DIM + d] = f2bf(acc);
    } else if (b < 384) {
        const int e = b - 256;
        float f = 0.f;
        for (int dd = 0; dd < DIM; ++dd)
            f = fmaf(Eemb[e * DIM + dd], W_node[(DIM + dd) * DIM + d], f);
        F[d] = f;
        __syncthreads();
        float acc = 0.f;
        for (int jj = 0; jj < DIM; ++jj)
            acc = fmaf(F[jj], attenW[jj * DIM + d], acc);
        Mhi[(DIM + e) * DIM + d] = f2bf(acc);
    } else if (b < 512) {
        const int e = b - 384;
        float acc = 0.f;
        for (int dd = 0; dd < DIM; ++dd)
            acc = fmaf(Eemb[e * DIM + dd], W_nb[(DIM + dd) * DIM + d], acc);
        WnbTh2[d * KZ + DIM + e] = f2bf(acc);
    } else {
        // X pack: float4 -> short4, 1048576 vec4 units, exactly 2 iters/thread
        const int XN4 = (N_NODES * DIM) / 4;
        for (int i = (b - 512) * 256 + d; i < XN4; i += 2048 * 256) {
            float4 v = ((const float4*)X)[i];
            short4v s = {(short)f2bf(v.x), (short)f2bf(v.y),
                         (short)f2bf(v.z), (short)f2bf(v.w)};
            ((short4v*)Xh)[i] = s;
        }
        // small transposed packs
        const int WE = DIM * DIM;            // 65536
        const int WE1 = 64 * DIM;            // 16384
        for (int i = (b - 512) * 256 + d; i < WE + WE1; i += 2048 * 256) {
            if (i < WE) {
                int c = i >> 8, k = i & 255;
                WnbTh2[c * KZ + k] = f2bf(W_nb[k * DIM + c]);
            } else {
                int j = i - WE;              // j = n*256 + k, n<64
                int n = j >> 8, k = j & 255;
                W1h[j] = f2bf(W1[k * 64 + n]);
            }
        }
    }
}

// ---------------------------------------------------------------------------
// gemm_z: [z1|EZ][16384,384] = Xh @ Mcat^T (single bf16 product).
// 2D grid (128,3), x-major (R17 lesson: col-adjacent 1D order put
// panel-sharing blocks on different XCDs -> A-traffic x3 -> +8us).
// Epilogue: col<256 -> Zh bf16; col>=256 -> EZh bf16.
// ---------------------------------------------------------------------------
__global__ __launch_bounds__(256, 2) void gemm_z(const u16* __restrict__ Xh,
                                                 const u16* __restrict__ Mhi,
                                                 u16* __restrict__ Zh,
                                                 u16* __restrict__ EZh) {
    constexpr int BM = 128, BN = 128, BK = 64;
    constexpr int Kd = DIM;
    __shared__ short Ah[BM * BK], Bh[BN * BK];
    const int tid = threadIdx.x;
    const int m0 = blockIdx.x * BM, n0 = blockIdx.y * BN;
    const int w = tid >> 6, lane = tid & 63;
    const int wr = (w >> 1) * 64, wc = (w & 1) * 64;
    const int lrow = lane & 15, lkg = lane >> 4;

    f32x4 acc[4][4] = {};

    for (int k0 = 0; k0 < Kd; k0 += BK) {
#pragma unroll
        for (int i = 0; i < 4; ++i) {
            int idx = i * 256 + tid;
            int r = idx >> 3, c8 = (idx & 7) << 3;
            int li = lds_swz(r, c8);
            *(short8v*)&Ah[li] = *(const short8v*)&Xh[(size_t)(m0 + r) * Kd + k0 + c8];
            *(short8v*)&Bh[li] = *(const short8v*)&Mhi[(size_t)(n0 + r) * Kd + k0 + c8];
        }
        __syncthreads();
#pragma unroll
        for (int kk = 0; kk < 2; ++kk) {
            const int kof = kk * 32 + lkg * 8;
            bf16x8 a[4], b[4];
#pragma unroll
            for (int i = 0; i < 4; ++i) a[i] = *(const bf16x8*)&Ah[lds_swz(wr + i * 16 + lrow, kof)];
#pragma unroll
            for (int j = 0; j < 4; ++j) b[j] = *(const bf16x8*)&Bh[lds_swz(wc + j * 16 + lrow, kof)];
#pragma unroll
            for (int i = 0; i < 4; ++i)
#pragma unroll
                for (int j = 0; j < 4; ++j)
                    acc[i][j] = __builtin_amdgcn_mfma_f32_16x16x32_bf16(a[i], b[j], acc[i][j], 0, 0, 0);
        }
        __syncthreads();
    }
#pragma unroll
    for (int i = 0; i < 4; ++i)
#pragma unroll
        for (int j = 0; j < 4; ++j)
#pragma unroll
            for (int r = 0; r < 4; ++r) {
                int row = m0 + wr + i * 16 + lkg * 4 + r;
                int col = n0 + wc + j * 16 + lrow;
                if (col < DIM)
                    Zh[(size_t)row * DIM + col] = f2bf(acc[i][j][r]);
                else
                    EZh[(size_t)row * NEDGE + (col - DIM)] = f2bf(acc[i][j][r]);
            }
}

// ---------------------------------------------------------------------------
// gather_fused v7: loop1 = flash-style logit + out-aggregation; loop2 =
// in-aggregation + in-edge histogram (dependency-free from loop1); out-edge
// histogram = load-free readlane sweep after softmax. No fences, no local
// arrays, no LDS. 8 waves/block.
// ---------------------------------------------------------------------------
#define NPB 8
__global__ __launch_bounds__(64 * NPB) void gather_fused(
    const u16* __restrict__ Xh, const u16* __restrict__ Zh,
    const u16* __restrict__ EZh,
    const int* __restrict__ in_idx, const int* __restrict__ in_edge,
    const float* __restrict__ in_mask, const int* __restrict__ out_idx,
    const int* __restrict__ out_edge, const float* __restrict__ out_mask,
    u16* __restrict__ REPh) {
    const int tid = threadIdx.x;
    const int w = tid >> 6, lane = tid & 63;
    const int n = blockIdx.x * NPB + w;
    const int nu = __builtin_amdgcn_readfirstlane(n);
    const int l31 = lane & 31, h = lane >> 5;
    const int l15 = lane & 15;

    // per-lane tables: lane l15 holds neighbor-l15 entry (readlane sources)
    const int oi_l = out_idx[nu * KNBR + l15];
    const int ii_l = in_idx[nu * KNBR + l15];
    const float om_l = out_mask[nu * KNBR + l15];
    const float im_l = in_mask[nu * KNBR + l15];
    const int oe_l = out_edge[nu * KNBR + l15];
    const int ie_l = in_edge[nu * KNBR + l15];
    const float ez_l = bf2f(EZh[(size_t)n * NEDGE + oe_l]);   // EZ for k=l15
    const int k_lane = ((lane & 7) << 1) | h;
    const float om_v = out_mask[nu * KNBR + k_lane];

    // z1 slice: lane covers dims [8*l31, 8*l31+8)
    float zr[8];
    {
        short8v zvv = *(const short8v*)&Zh[(size_t)n * DIM + l31 * 8];
#pragma unroll
        for (int c = 0; c < 8; ++c) zr[c] = bf2f((u16)zvv[c]);
    }

    const char* Xb = (const char*)Xh;
    const u32 lofs = (u32)l31 * 16u;

    // loop1: fused logit + out-aggregation; iter j covers k=2j (lanes 0-31)
    // and k=2j+1 (lanes 32-63); row consumed for BOTH in one pass.
    float acc_o[8] = {};
    float s_run = 0.f, esel = 0.f;
#pragma unroll
    for (int j = 0; j < 8; ++j) {
        const int ro0 = __builtin_amdgcn_readlane(oi_l, 2 * j);
        const int ro1 = __builtin_amdgcn_readlane(oi_l, 2 * j + 1);
        const int ro = h ? ro1 : ro0;
        u32x4 xv = *(const u32x4*)(Xb + (((u32)ro << 9) + lofs));
        short8v sv = __builtin_bit_cast(short8v, xv);
        float q = 0.f;
#pragma unroll
        for (int c = 0; c < 8; ++c) q = fmaf(bf2f((u16)sv[c]), zr[c], q);
        q += __shfl_xor(q, 1);
        q += __shfl_xor(q, 2);
        q += __shfl_xor(q, 4);
        q += __shfl_xor(q, 8);
        q += __shfl_xor(q, 16);
        const float ez0 = readlane_f(ez_l, 2 * j);
        const float ez1 = readlane_f(ez_l, 2 * j + 1);
        q += h ? ez1 : ez0;
        const float eo = __expf(q);              // unnormalized weight, own k
        const float ec = __shfl_xor(eo, 32);     // other half's e
        s_run += eo + ec;                        // adds e(2j)+e(2j+1) once
        if ((lane & 7) == j) esel = eo;          // keep e for k_lane
        const float om0 = readlane_f(om_l, 2 * j);
        const float om1 = readlane_f(om_l, 2 * j + 1);
        const float wgt = eo * (h ? om1 : om0);
#pragma unroll
        for (int c = 0; c < 8; ++c) acc_o[c] = fmaf(wgt, bf2f((u16)sv[c]), acc_o[c]);
    }

    // loop2: in-aggregation + in-edge histogram — independent of loop1.
    float acc_i[8] = {};
    const int my0 = 2 * lane, my1 = 2 * lane + 1;
    float hb0 = 0.f, hb1 = 0.f;
#pragma unroll
    for (int j = 0; j < 8; ++j) {
        const int ri0 = __builtin_amdgcn_readlane(ii_l, 2 * j);
        const int ri1 = __builtin_amdgcn_readlane(ii_l, 2 * j + 1);
        const int ri = h ? ri1 : ri0;
        u32x4 xv = *(const u32x4*)(Xb + (((u32)ri << 9) + lofs));
        short8v sv = __builtin_bit_cast(short8v, xv);
        const float im0 = readlane_f(im_l, 2 * j);
        const float im1 = readlane_f(im_l, 2 * j + 1);
        const float imk = h ? im1 : im0;
#pragma unroll
        for (int c = 0; c < 8; ++c) acc_i[c] = fmaf(imk, bf2f((u16)sv[c]), acc_i[c]);
        const int ie0 = __builtin_amdgcn_readlane(ie_l, 2 * j);
        const int ie1 = __builtin_amdgcn_readlane(ie_l, 2 * j + 1);
        hb0 += (ie0 == my0 ? im0 : 0.f) + (ie1 == my0 ? im1 : 0.f);
        hb1 += (ie0 == my1 ? im0 : 0.f) + (ie1 == my1 ? im1 : 0.f);
    }

    // softmax scalars (only now needed)
    const float inv_s = 1.0f / s_run;
    const float wt = esel * om_v * inv_s;        // alpha*om for k_lane

    // out-edge histogram: load-free readlane+cmp sweep
#pragma unroll
    for (int k = 0; k < KNBR; ++k) {
        const int lk = (k & 1) * 32 + (k >> 1);  // lane holding k's wt
        const float wtk = readlane_f(wt, lk);
        const int oek = __builtin_amdgcn_readlane(oe_l, k);
        hb0 += (oek == my0 ? wtk : 0.f);
        hb1 += (oek == my1 ? wtk : 0.f);
    }

    // fold halves; REPnode = out/s + in, from lanes 0-31
#pragma unroll
    for (int c = 0; c < 8; ++c) {
        float to = acc_o[c] + __shfl_xor(acc_o[c], 32);
        float ti = acc_i[c] + __shfl_xor(acc_i[c], 32);
        acc_o[c] = to * inv_s + ti;
    }
    if (lane < 32) {
        short8v ov;
#pragma unroll
        for (int c = 0; c < 8; ++c) ov[c] = (short)f2bf(acc_o[c]);
        *(short8v*)&REPh[(size_t)n * KZ + l31 * 8] = ov;
    }
    u32 pk = (u32)f2bf(hb0) | ((u32)f2bf(hb1) << 16);
    *(u32*)&REPh[(size_t)n * KZ + DIM + lane * 2] = pk;
}

// ---------------------------------------------------------------------------
// gemm_h: out[16384,256] f32 = [REPnode|cnt] @ WnbTh2^T + Xh + 2*b_nb;
// residual from bf16 Xh. Also writes Hh bf16 (MFMA MLP). K=384.
// 2D grid (128,2), x-major (R17 revert).
// ---------------------------------------------------------------------------
__global__ __launch_bounds__(256, 3) void gemm_h(const u16* __restrict__ A,
                                                 const u16* __restrict__ B,
                                                 const u16* __restrict__ Xres,
                                                 const float* __restrict__ b_nb,
                                                 float* __restrict__ out,
                                                 u16* __restrict__ Hh) {
    constexpr int BM = 128, BN = 128, BK = 64;
    constexpr int Kd = KZ, Nd = DIM;
    __shared__ short Ah[BM * BK], Bh[BN * BK];
    const int tid = threadIdx.x;
    const int m0 = blockIdx.x * BM, n0 = blockIdx.y * BN;
    const int w = tid >> 6, lane = tid & 63;
    const int wr = (w >> 1) * 64, wc = (w & 1) * 64;
    const int lrow = lane & 15, lkg = lane >> 4;

    f32x4 acc[4][4] = {};

    for (int k0 = 0; k0 < Kd; k0 += BK) {
#pragma unroll
        for (int i = 0; i < 4; ++i) {
            int idx = i * 256 + tid;
            int r = idx >> 3, c8 = (idx & 7) << 3;
            int li = lds_swz(r, c8);
            *(short8v*)&Ah[li] = *(const short8v*)&A[(size_t)(m0 + r) * Kd + k0 + c8];
            *(short8v*)&Bh[li] = *(const short8v*)&B[(size_t)(n0 + r) * Kd + k0 + c8];
        }
        __syncthreads();
#pragma unroll
        for (int kk = 0; kk < 2; ++kk) {
            const int kof = kk * 32 + lkg * 8;
            bf16x8 a[4], b[4];
#pragma unroll
            for (int i = 0; i < 4; ++i) a[i] = *(const bf16x8*)&Ah[lds_swz(wr + i * 16 + lrow, kof)];
#pragma unroll
            for (int j = 0; j < 4; ++j) b[j] = *(const bf16x8*)&Bh[lds_swz(wc + j * 16 + lrow, kof)];
#pragma unroll
            for (int i = 0; i < 4; ++i)
#pragma unroll
                for (int j = 0; j < 4; ++j)
                    acc[i][j] = __builtin_amdgcn_mfma_f32_16x16x32_bf16(a[i], b[j], acc[i][j], 0, 0, 0);
        }
        __syncthreads();
    }
#pragma unroll
    for (int i = 0; i < 4; ++i)
#pragma unroll
        for (int j = 0; j < 4; ++j)
#pragma unroll
            for (int r = 0; r < 4; ++r) {
                int row = m0 + wr + i * 16 + lkg * 4 + r;
                int col = n0 + wc + j * 16 + lrow;
                size_t off = (size_t)row * Nd + col;
                float hv = acc[i][j][r] + bf2f(Xres[off]) + 2.0f * b_nb[col];
                out[off] = hv;
                Hh[off] = f2bf(hv);
            }
}

// ---------------------------------------------------------------------------
// mlp_mfma + finalize: unchanged (deterministic 2-stage readout).
// ---------------------------------------------------------------------------
__global__ __launch_bounds__(256) void mlp_mfma(const u16* __restrict__ Hh,
                                                const u16* __restrict__ W1h,
                                                const float* __restrict__ b1,
                                                const float* __restrict__ W2,
                                                float* __restrict__ partials) {
    constexpr int BM = 128, BN = 64, BK = 64;
    constexpr int Kd = DIM;
    __shared__ short Ah[BM * BK], Bh[BN * BK];
    __shared__ float red[4][BN];
    const int tid = threadIdx.x;
    const int m0 = blockIdx.x * BM;
    const int w = tid >> 6, lane = tid & 63;
    const int wr = w * 32;
    const int lrow = lane & 15, lkg = lane >> 4;

    f32x4 acc[2][4] = {};

    for (int k0 = 0; k0 < Kd; k0 += BK) {
#pragma unroll
        for (int i = 0; i < 4; ++i) {
            int idx = i * 256 + tid;
            int r = idx >> 3, c8 = (idx & 7) << 3;
            *(short8v*)&Ah[lds_swz(r, c8)] =
                *(const short8v*)&Hh[(size_t)(m0 + r) * Kd + k0 + c8];
        }
#pragma unroll
        for (int i = 0; i < 2; ++i) {
            int idx = i * 256 + tid;
            if (idx < 512) {
                int r = idx >> 3, c8 = (idx & 7) << 3;
                *(short8v*)&Bh[lds_swz(r, c8)] =
                    *(const short8v*)&W1h[(size_t)r * Kd + k0 + c8];
            }
        }
        __syncthreads();
#pragma unroll
        for (int kk = 0; kk < 2; ++kk) {
            const int kof = kk * 32 + lkg * 8;
            bf16x8 a[2], b[4];
#pragma unroll
            for (int i = 0; i < 2; ++i) a[i] = *(const bf16x8*)&Ah[lds_swz(wr + i * 16 + lrow, kof)];
#pragma unroll
            for (int j = 0; j < 4; ++j) b[j] = *(const bf16x8*)&Bh[lds_swz(j * 16 + lrow, kof)];
#pragma unroll
            for (int i = 0; i < 2; ++i)
#pragma unroll
                for (int j = 0; j < 4; ++j)
                    acc[i][j] = __builtin_amdgcn_mfma_f32_16x16x32_bf16(a[i], b[j], acc[i][j], 0, 0, 0);
        }
        __syncthreads();
    }
    float cs[4];
#pragma unroll
    for (int j = 0; j < 4; ++j) {
        const float bj = b1[j * 16 + lrow];
        float sv = 0.f;
#pragma unroll
        for (int i = 0; i < 2; ++i)
#pragma unroll
            for (int r = 0; r < 4; ++r) sv += fmaxf(acc[i][j][r] + bj, 0.f);
        cs[j] = sv;
    }
#pragma unroll
    for (int j = 0; j < 4; ++j) {
        cs[j] += __shfl_xor(cs[j], 16);
        cs[j] += __shfl_xor(cs[j], 32);
    }
    if (lkg == 0) {
#pragma unroll
        for (int j = 0; j < 4; ++j) red[w][j * 16 + lrow] = cs[j];
    }
    __syncthreads();
    if (tid < 64) {
        float t = red[0][tid] + red[1][tid] + red[2][tid] + red[3][tid];
        float h0 = t * W2[tid * 2 + 0];
        float h1 = t * W2[tid * 2 + 1];
#pragma unroll
        for (int off = 32; off > 0; off >>= 1) {
            h0 += __shfl_down(h0, off);
            h1 += __shfl_down(h1, off);
        }
        if (tid == 0) {
            partials[blockIdx.x * 2 + 0] = h0;
            partials[blockIdx.x * 2 + 1] = h1;
        }
    }
}

__global__ void finalize(const float* __restrict__ partials,
                         const float* __restrict__ b2, float* __restrict__ out) {
    const int l = threadIdx.x;
    float h0 = 0.f, h1 = 0.f;
    for (int i = l; i < 128; i += 64) {
        h0 += partials[2 * i + 0];
        h1 += partials[2 * i + 1];
    }
#pragma unroll
    for (int off = 32; off > 0; off >>= 1) {
        h0 += __shfl_down(h0, off);
        h1 += __shfl_down(h1, off);
    }
    if (l == 0) {
        h0 += (float)N_NODES * b2[0];
        h1 += (float)N_NODES * b2[1];
        const float m = fmaxf(h0, h1);
        const float e0 = __expf(h0 - m), e1 = __expf(h1 - m);
        out[(size_t)N_NODES * DIM + 0] = e0 / (e0 + e1);
        out[(size_t)N_NODES * DIM + 1] = e1 / (e0 + e1);
    }
}

extern "C" void kernel_launch(void* const* d_in, const int* in_sizes, int n_in,
                              void* d_out, int out_size, void* d_ws, size_t ws_size,
                              hipStream_t stream) {
    const float* X = (const float*)d_in[0];
    const int* in_idx = (const int*)d_in[1];
    const int* in_edge = (const int*)d_in[2];
    const float* in_mask = (const float*)d_in[3];
    const int* out_idx = (const int*)d_in[4];
    const int* out_edge = (const int*)d_in[5];
    const float* out_mask = (const float*)d_in[6];
    const float* Eemb = (const float*)d_in[7];
    const float* W_nb = (const float*)d_in[8];
    const float* b_nb = (const float*)d_in[9];
    const float* W_node = (const float*)d_in[10];
    // d_in[11] = b_node: softmax-invariant -> unused
    const float* attenW = (const float*)d_in[12];
    const float* W1 = (const float*)d_in[13];
    const float* b1 = (const float*)d_in[14];
    const float* W2 = (const float*)d_in[15];
    const float* b2 = (const float*)d_in[16];
    float* out = (float*)d_out;

    char* ws = (char*)d_ws;
    // Overlays (stream-ordered): Zh+EZh dead after gather_fused -> Hh reuses.
    u16* Zh = (u16*)ws;                          // 8 MiB   [0, 8M)
    u16* EZh = (u16*)(ws + 8388608);             // 4 MiB   [8M, 12M)
    u16* Hh = (u16*)ws;                          // 8 MiB   [0, 8M) reuse
    u16* REPh = (u16*)(ws + 16777216);           // 12.58 MiB
    u16* Xh = (u16*)(ws + 29360128);             // 8 MiB
    u16* WnbTh2 = (u16*)(ws + 37748736);         // 192 KiB (256x384)
    u16* Mhi = (u16*)(ws + 37945344);            // 192 KiB (384x256)
    u16* W1h = (u16*)(ws + 38338560);            // 32 KiB
    float* partials = (float*)(ws + 38371328);   // 1 KiB

    prep<<<2560, 256, 0, stream>>>(X, W_nb, W1, W_node, attenW, Eemb,
                                   Xh, WnbTh2, W1h, Mhi);
    gemm_z<<<dim3(128, 3), 256, 0, stream>>>(Xh, Mhi, Zh, EZh);
    gather_fused<<<N_NODES / NPB, 64 * NPB, 0, stream>>>(
        Xh, Zh, EZh, in_idx, in_edge, in_mask, out_idx, out_edge, out_mask, REPh);
    gemm_h<<<dim3(128, 2), 256, 0, stream>>>(REPh, WnbTh2, Xh, b_nb, out, Hh);
    mlp_mfma<<<N_NODES / 128, 256, 0, stream>>>(Hh, W1h, b1, W2, partials);
    finalize<<<1, 64, 0, stream>>>(partials, b2, out);
}